// Round 11
// baseline (25.198 us; speedup 1.0000x reference)
//
#include <hip/hip_runtime.h>
#include <math.h>

#define NB 512
#define HW 169
#define NA 5
#define NCH 125
#define BLOCK 256
#define NBLOCKS ((NB * HW) / BLOCK)   // 338
#define REC 8                          // padded per-block record (dwords)

// Anchors are compile-time constants in the reference — bake them in.
__device__ __constant__ const float ANC_W[NA] = {1.3221f, 3.19275f, 5.05587f, 9.47112f, 11.2364f};
__device__ __constant__ const float ANC_H[NA] = {1.73145f, 4.00944f, 8.09892f, 4.84053f, 10.0071f};

#define NTLOAD(p) __builtin_nontemporal_load(p)

__global__ __launch_bounds__(BLOCK, 2) void yolo_loss_main(
    const float* __restrict__ P,    // [B][125][169] (channel-major)
    const float* __restrict__ T,    // [B][169][125]
    float* __restrict__ brec)       // [NBLOCKS][REC]
{
    int t = threadIdx.x;
    int idx = blockIdx.x * BLOCK + t;
    int b  = idx / HW;
    int hw = idx - b * HW;

    const float* Pb = P + (size_t)b * NCH * HW + hw;
    const float* Tb = T + ((size_t)b * HW + hw) * NCH;

    // ---- phase 1: all 45 independent loads, nontemporal (L1-bypass -> deeper
    //      miss concurrency; data is cold-HBM every replay, L1 reuse is nil)
    float gx[NA], gy[NA], gw_[NA], gh[NA], gc[NA];
    float rx[NA], ry[NA], rw[NA], rh[NA];
#pragma unroll
    for (int a = 0; a < NA; ++a) {
        int c0 = a * 25;
        gc[a]  = NTLOAD(Tb + c0 + 20);
        gx[a]  = NTLOAD(Tb + c0 + 21);
        gy[a]  = NTLOAD(Tb + c0 + 22);
        gw_[a] = NTLOAD(Tb + c0 + 23);
        gh[a]  = NTLOAD(Tb + c0 + 24);
    }
#pragma unroll
    for (int a = 0; a < NA; ++a) {
        int c0 = a * 25;
        rx[a] = NTLOAD(Pb + (c0 + 21) * HW);
        ry[a] = NTLOAD(Pb + (c0 + 22) * HW);
        rw[a] = NTLOAD(Pb + (c0 + 23) * HW);
        rh[a] = NTLOAD(Pb + (c0 + 24) * HW);
    }

    // ---- phase 2: transforms
    float px[NA], py[NA], pw[NA], ph[NA];
#pragma unroll
    for (int a = 0; a < NA; ++a) {
        px[a] = 1.0f / (1.0f + expf(-rx[a]));
        py[a] = 1.0f / (1.0f + expf(-ry[a]));
        pw[a] = expf(rw[a]);
        ph[a] = expf(rh[a]);
    }

    float contrib[NA];
    int cmask = 0;
#pragma unroll
    for (int i = 0; i < NA; ++i) {
        float aw = ANC_W[i], ah = ANC_H[i];
        float ax1 = px[i] - aw * 0.5f, ax2 = px[i] + aw * 0.5f;
        float ay1 = py[i] - ah * 0.5f, ay2 = py[i] + ah * 0.5f;
        float area_a = (ax2 - ax1) * (ay2 - ay1);
        float best = -1.0f; int bestj = 0;
#pragma unroll
        for (int j = 0; j < NA; ++j) {
            float bx1 = gx[j] - gw_[j] * 0.5f, bx2 = gx[j] + gw_[j] * 0.5f;
            float by1 = gy[j] - gh[j] * 0.5f, by2 = gy[j] + gh[j] * 0.5f;
            float iw = fmaxf(fminf(ax2, bx2) - fmaxf(ax1, bx1), 0.0f);
            float ih = fmaxf(fminf(ay2, by2) - fmaxf(ay1, by1), 0.0f);
            float inter = iw * ih;
            float area_b = (bx2 - bx1) * (by2 - by1);
            float iou = inter / (area_a + area_b - inter + 1e-10f);
            if (iou > best) { best = iou; bestj = j; }   // strict > == jnp.argmax first-max
        }
        cmask |= (1 << bestj);
        float dx = px[i] - gx[i], dy = py[i] - gy[i];
        float dw = pw[i] - gw_[i], dh = ph[i] - gh[i];
        contrib[i] = gc[i] * gc[i] * (dx * dx + dy * dy + dw * dw + dh * dh);
    }

    // ---- phase 3: wave shuffle reduce -> cross-wave via LDS -> 32-B record
    __shared__ float sred[4][NA];
    __shared__ int smask[4];
    int lane = t & 63, wid = t >> 6;

#pragma unroll
    for (int i = 0; i < NA; ++i) {
        float v = contrib[i];
        for (int off = 32; off; off >>= 1) v += __shfl_down(v, off, 64);
        if (lane == 0) sred[wid][i] = v;
    }
    for (int off = 32; off; off >>= 1) cmask |= __shfl_down(cmask, off, 64);
    if (lane == 0) smask[wid] = cmask;
    __syncthreads();

    if (t == 0) {
        int m = smask[0] | smask[1] | smask[2] | smask[3];
        float4* r4 = (float4*)(brec + blockIdx.x * REC);
        r4[0] = make_float4(sred[0][0] + sred[1][0] + sred[2][0] + sred[3][0],
                            sred[0][1] + sred[1][1] + sred[2][1] + sred[3][1],
                            sred[0][2] + sred[1][2] + sred[2][2] + sred[3][2],
                            sred[0][3] + sred[1][3] + sred[2][3] + sred[3][3]);
        r4[1] = make_float4(sred[0][4] + sred[1][4] + sred[2][4] + sred[3][4],
                            __int_as_float(m), 0.0f, 0.0f);
    }
}

__global__ void yolo_loss_final(const float* __restrict__ brec,
                                float* __restrict__ out)
{
    int lane = threadIdx.x;          // one 64-lane wave
    const float4* r4 = (const float4*)brec;
    double s[NA] = {0, 0, 0, 0, 0};
    int m = 0;
    for (int e = lane; e < NBLOCKS; e += 64) {
        float4 lo = r4[e * 2];
        float4 hi = r4[e * 2 + 1];
        s[0] += (double)lo.x; s[1] += (double)lo.y;
        s[2] += (double)lo.z; s[3] += (double)lo.w;
        s[4] += (double)hi.x;
        m |= __float_as_int(hi.y);
    }
#pragma unroll
    for (int i = 0; i < NA; ++i)
        for (int off = 32; off; off >>= 1) s[i] += __shfl_down(s[i], off, 64);
    for (int off = 32; off; off >>= 1) m |= __shfl_down(m, off, 64);

    if (lane == 0) {
        double tot = 0.0;
#pragma unroll
        for (int i = 0; i < NA; ++i)
            if ((m >> i) & 1) tot += s[i];
        out[0] = (float)((5.0 / 512.0) * tot);
    }
}

extern "C" void kernel_launch(void* const* d_in, const int* in_sizes, int n_in,
                              void* d_out, int out_size, void* d_ws, size_t ws_size,
                              hipStream_t stream) {
    const float* P   = (const float*)d_in[0];
    const float* T   = (const float*)d_in[1];
    float* out = (float*)d_out;

    float* brec = (float*)d_ws;   // NBLOCKS * REC floats

    yolo_loss_main<<<NBLOCKS, BLOCK, 0, stream>>>(P, T, brec);
    yolo_loss_final<<<1, 64, 0, stream>>>(brec, out);
}